// Round 18
// baseline (316.067 us; speedup 1.0000x reference)
//
#include <hip/hip_runtime.h>
#include <cstdint>
#include <cstddef>

#define NEG_SLOPE 0.2f

typedef unsigned short ushortT;
typedef unsigned int uintT;

// round-to-nearest-even f32 -> bf16 bits (finite values)
__device__ __forceinline__ ushortT f2bf(float f) {
    uintT u = __float_as_uint(f);
    uintT r = (u + 0x7fffu + ((u >> 16) & 1u)) >> 16;
    return (ushortT)r;
}

// ---------------------------------------------------------------------------
// CSR build (2 kernels + 1KB memset): fixed-capacity per-bucket regions.
// bucket = 512 consecutive dst nodes; packed entry = (local_dst<<17)|src
// ---------------------------------------------------------------------------
#define CAP_LOG 14
#define CAP (1 << CAP_LOG)
#define FILL_CAP 12288

#define BIN_K 16   // edges per thread; chunk = 256*16 = 4096
__global__ __launch_bounds__(256) void bin_edges(
    const int* __restrict__ ei, int* __restrict__ bcur,
    int* __restrict__ ebuf, int E, int total) {
    __shared__ int lhist[256];
    __shared__ int lbase[256];
    int tid = threadIdx.x;
    lhist[tid] = 0;
    __syncthreads();
    int base_e = blockIdx.x * (256 * BIN_K);
    int pk[BIN_K], bk[BIN_K];
#pragma unroll
    for (int k = 0; k < BIN_K; ++k) {
        int e = base_e + tid + k * 256;
        bool v = e < total;
        int ee = v ? e : 0;
        int s, d;
        if (ee < E) { s = ei[ee]; d = ei[E + ee]; }
        else        { s = d = ee - E; }
        pk[k] = ((d & 511) << 17) | s;
        bk[k] = v ? (d >> 9) : -1;
        if (v) atomicAdd(&lhist[bk[k]], 1);
    }
    __syncthreads();
    int h = lhist[tid];
    lbase[tid] = (h > 0) ? atomicAdd(&bcur[tid], h) : 0;
    __syncthreads();
    lhist[tid] = 0;
    __syncthreads();
#pragma unroll
    for (int k = 0; k < BIN_K; ++k) {
        if (bk[k] >= 0) {
            int r = atomicAdd(&lhist[bk[k]], 1);
            ebuf[((size_t)bk[k] << CAP_LOG) + lbase[bk[k]] + r] = pk[k];
        }
    }
}

__global__ __launch_bounds__(256) void local_fill4(
    const int* __restrict__ ebuf, const int* __restrict__ bcur,
    int* __restrict__ rp, int* __restrict__ cs, int n, int nb) {
    __shared__ int ebloc[FILL_CAP];
    __shared__ int lhist[512];
    __shared__ int lscan[256];
    __shared__ int lcur[512];
    int b = blockIdx.x;
    int tid = threadIdx.x;
    int node0 = b * 512;
    int nodes = min(512, n - node0);

    int c = (tid < nb) ? bcur[tid] : 0;
    lscan[tid] = c;
    __syncthreads();
    for (int off = 1; off < 256; off <<= 1) {
        int x = (tid >= off) ? lscan[tid - off] : 0;
        __syncthreads();
        lscan[tid] += x;
        __syncthreads();
    }
    int gbase = (b > 0) ? lscan[b - 1] : 0;
    int cnt   = lscan[b] - gbase;
    int total = lscan[nb - 1];
    __syncthreads();

    const int* src_e = ebuf + ((size_t)b << CAP_LOG);
    lhist[tid] = 0; lhist[tid + 256] = 0;
    for (int j = tid; j < cnt && j < FILL_CAP; j += 256)
        ebloc[j] = src_e[j];
    __syncthreads();

    for (int j = tid; j < cnt; j += 256) {
        int v = (j < FILL_CAP) ? ebloc[j] : src_e[j];
        atomicAdd(&lhist[v >> 17], 1);
    }
    __syncthreads();

    int a0 = lhist[2 * tid], a1 = lhist[2 * tid + 1];
    int psum = a0 + a1;
    lscan[tid] = psum;
    __syncthreads();
    for (int off = 1; off < 256; off <<= 1) {
        int x = (tid >= off) ? lscan[tid - off] : 0;
        __syncthreads();
        lscan[tid] += x;
        __syncthreads();
    }
    int e0 = gbase + (lscan[tid] - psum);
    int e1 = e0 + a0;
    if (2 * tid < nodes)     rp[node0 + 2 * tid]     = e0;
    if (2 * tid + 1 < nodes) rp[node0 + 2 * tid + 1] = e1;
    lcur[2 * tid] = e0;
    lcur[2 * tid + 1] = e1;
    if (b == 0 && tid == 0) rp[n] = total;
    __syncthreads();

    for (int j = tid; j < cnt; j += 256) {
        int v = (j < FILL_CAP) ? ebloc[j] : src_e[j];
        int pos = atomicAdd(&lcur[v >> 17], 1);
        cs[pos] = v & 0x1FFFF;
    }
}

// ---------------------------------------------------------------------------
// Fused projection + attention dots:  h(bf16) = x @ W ; hs/hd from f32 acc.
// Software-pipelined k-loop: xa/xb named register double-buffer; loads for
// chunk k+4 issued BEFORE the FMA block consuming chunk k.
// `#pragma unroll 1` keeps the loop rolled (one alternation, <=8 loads in
// flight); __launch_bounds__(NT, 6) caps the allocator at ~85 VGPR so the
// compiler cannot hoist/unroll into a register explosion (R17 lesson).
// ---------------------------------------------------------------------------
template <int INF, int OUTF, int NPB>
__global__ __launch_bounds__(OUTF / 4 * (NPB / 4), 6) void gemm_attn(
    const float* __restrict__ x, const float* __restrict__ W,
    const float* __restrict__ a_s, const float* __restrict__ a_d,
    ushortT* __restrict__ h, float* __restrict__ hs,
    float* __restrict__ hd, int n) {
    constexpr int FC = OUTF / 4;
    constexpr int NT = FC * (NPB / 4);
    __shared__ float Wl[INF * OUTF];
    int tid = threadIdx.x;
    for (int i = tid; i < INF * OUTF; i += NT) Wl[i] = W[i];
    __syncthreads();

    int fc = tid % FC;
    int nc = tid / FC;
    int n0 = blockIdx.x * NPB + nc * 4;
    int ni[4];
#pragma unroll
    for (int i = 0; i < 4; ++i) { int v = n0 + i; ni[i] = (v < n) ? v : (n - 1); }

    float acc[4][4] = {};
    float4 xa[4], xb[4];

#define LOADX(buf, koff)                                                    \
    _Pragma("unroll")                                                       \
    for (int i = 0; i < 4; ++i)                                             \
        buf[i] = *reinterpret_cast<const float4*>(&x[(size_t)ni[i] * INF + (koff)]);

#define FMABLK(buf, kbase)                                                  \
    _Pragma("unroll")                                                       \
    for (int j = 0; j < 4; ++j) {                                           \
        float4 wv = *reinterpret_cast<const float4*>(                       \
            &Wl[((kbase) + j) * OUTF + fc * 4]);                            \
        _Pragma("unroll")                                                   \
        for (int i = 0; i < 4; ++i) {                                       \
            float xs = (&buf[i].x)[j];                                      \
            acc[i][0] = fmaf(xs, wv.x, acc[i][0]);                          \
            acc[i][1] = fmaf(xs, wv.y, acc[i][1]);                          \
            acc[i][2] = fmaf(xs, wv.z, acc[i][2]);                          \
            acc[i][3] = fmaf(xs, wv.w, acc[i][3]);                          \
        }                                                                   \
    }

    LOADX(xa, 0);
#pragma unroll 1
    for (int kc = 0; kc < INF; kc += 8) {
        LOADX(xb, kc + 4);            // kc+4 < INF always (INF multiple of 8)
        FMABLK(xa, kc);
        if (kc + 8 < INF) { LOADX(xa, kc + 8); }
        FMABLK(xb, kc + 4);
    }
#undef LOADX
#undef FMABLK

    float asv[4], adv[4];
#pragma unroll
    for (int j = 0; j < 4; ++j) { asv[j] = a_s[fc * 4 + j]; adv[j] = a_d[fc * 4 + j]; }

#pragma unroll
    for (int i = 0; i < 4; ++i) {
        float ps = acc[i][0] * asv[0] + acc[i][1] * asv[1] +
                   acc[i][2] * asv[2] + acc[i][3] * asv[3];
        float pd = acc[i][0] * adv[0] + acc[i][1] * adv[1] +
                   acc[i][2] * adv[2] + acc[i][3] * adv[3];
#pragma unroll
        for (int off = FC >> 1; off; off >>= 1) {
            ps += __shfl_xor(ps, off, FC);
            pd += __shfl_xor(pd, off, FC);
        }
        int node = n0 + i;
        if (node < n) {
            ushort4 hv;
            hv.x = f2bf(acc[i][0]); hv.y = f2bf(acc[i][1]);
            hv.z = f2bf(acc[i][2]); hv.w = f2bf(acc[i][3]);
            *reinterpret_cast<ushort4*>(&h[(size_t)node * OUTF + fc * 4]) = hv;
            if (fc == 0) { hs[node] = ps; hd[node] = pd; }
        }
    }
}

// ---------------------------------------------------------------------------
// Multi-node-per-wave softmax aggregation over bf16 h rows, no online max
// (logits provably bounded |l|<~3). NPN node groups of LPN=64/NPN lanes;
// eL = F/8 lanes per edge (uint4 = 8 bf16 each); EPS = LPN/eL edges/step.
// ---------------------------------------------------------------------------
template <int F, int NPN>
__global__ __launch_bounds__(256) void aggregate_nf(
    const ushortT* __restrict__ hb, const float* __restrict__ hs,
    const float* __restrict__ hd, const int* __restrict__ rp,
    const int* __restrict__ cs, const float* __restrict__ b,
    float* __restrict__ out, int n) {
    constexpr int LPN = 64 / NPN;          // lanes per node group
    constexpr int eL  = F / 8;             // lanes per edge
    constexpr int EPS = LPN / eL;          // edges per step
    int wid  = (blockIdx.x * blockDim.x + threadIdx.x) >> 6;
    int lane = threadIdx.x & 63;
    int fl   = lane % LPN;
    int node = wid * NPN + lane / LPN;
    if (node >= n) return;
    int beg = rp[node], end = rp[node + 1];
    float hdn = hd[node];

    int grp = fl / eL;                     // 0..EPS-1: edge slot within step
    int sub = fl % eL;                     // feature-8-block index
    float4 bbA = *reinterpret_cast<const float4*>(&b[sub * 8]);
    float4 bbB = *reinterpret_cast<const float4*>(&b[sub * 8 + 4]);

    float sl = 0.f;                        // lane-local weight sum
    float acc[8] = {};

    for (int base = beg; base < end; base += LPN) {
        int e = base + fl;
        bool v = e < end;
        int src = cs[v ? e : beg];         // clamped: always a valid row

        float l = hs[src] + hdn;
        l = (l > 0.f) ? l : NEG_SLOPE * l;
        float w = v ? __expf(l) : 0.f;     // bounded: |l| < ~3
        sl += w;

        int cc = min(LPN, end - base);
        for (int t = 0; t * EPS < cc; t += 2) {
            uint4 hv[2];
            float wv[2];
#pragma unroll
            for (int u = 0; u < 2; ++u) {
                int jj = (t + u) * EPS + grp;       // < LPN by construction
                int   se = __shfl(src, jj, LPN);
                wv[u]    = __shfl(w,   jj, LPN);
                hv[u] = *reinterpret_cast<const uint4*>(&hb[(size_t)se * F + sub * 8]);
            }
#pragma unroll
            for (int u = 0; u < 2; ++u) {
                uintT q[4] = {hv[u].x, hv[u].y, hv[u].z, hv[u].w};
#pragma unroll
                for (int i = 0; i < 4; ++i) {
                    float lo = __uint_as_float(q[i] << 16);
                    float hi = __uint_as_float(q[i] & 0xffff0000u);
                    acc[2 * i]     = fmaf(wv[u], lo, acc[2 * i]);
                    acc[2 * i + 1] = fmaf(wv[u], hi, acc[2 * i + 1]);
                }
            }
        }
    }

#pragma unroll
    for (int off = LPN >> 1; off; off >>= 1)
        sl += __shfl_xor(sl, off, LPN);

#pragma unroll
    for (int off = eL; off < LPN; off <<= 1) {
#pragma unroll
        for (int i = 0; i < 8; ++i)
            acc[i] += __shfl_xor(acc[i], off, LPN);
    }

    float inv = 1.f / (sl + 1e-16f);
    if (grp == 0) {
        float4 rA, rB;
        rA.x = fmaxf(fmaf(acc[0], inv, bbA.x), 0.f);
        rA.y = fmaxf(fmaf(acc[1], inv, bbA.y), 0.f);
        rA.z = fmaxf(fmaf(acc[2], inv, bbA.z), 0.f);
        rA.w = fmaxf(fmaf(acc[3], inv, bbA.w), 0.f);
        rB.x = fmaxf(fmaf(acc[4], inv, bbB.x), 0.f);
        rB.y = fmaxf(fmaf(acc[5], inv, bbB.y), 0.f);
        rB.z = fmaxf(fmaf(acc[6], inv, bbB.z), 0.f);
        rB.w = fmaxf(fmaf(acc[7], inv, bbB.w), 0.f);
        *reinterpret_cast<float4*>(&out[(size_t)node * F + sub * 8])     = rA;
        *reinterpret_cast<float4*>(&out[(size_t)node * F + sub * 8 + 4]) = rB;
    }
}

// ---------------------------------------------------------------------------
// Global mean pool (batch is sorted): LDS pre-reduction then global atomics
// ---------------------------------------------------------------------------
__global__ void pool_kernel(const float* __restrict__ x, const int* __restrict__ batch,
                            float* __restrict__ pool, float* __restrict__ gcnt, int n) {
    __shared__ float lp[64 * 32];
    __shared__ float lc[64];
    int tid = threadIdx.x;
    for (int i = tid; i < 64 * 32; i += 256) lp[i] = 0.f;
    if (tid < 64) lc[tid] = 0.f;
    __syncthreads();
    int f = tid % 32, r = tid / 32;
    int base = blockIdx.x * 64;
    for (int i = r; i < 64; i += 8) {
        int node = base + i;
        if (node < n) {
            int g = batch[node];
            atomicAdd(&lp[g * 32 + f], x[(size_t)node * 32 + f]);
            if (f == 0) atomicAdd(&lc[g], 1.f);
        }
    }
    __syncthreads();
    for (int i = tid; i < 64 * 32; i += 256)
        if (lp[i] != 0.f) atomicAdd(&pool[i], lp[i]);
    if (tid < 64 && lc[tid] != 0.f) atomicAdd(&gcnt[tid], lc[tid]);
}

__global__ void finalize(const float* __restrict__ pool, const float* __restrict__ gcnt,
                         float* __restrict__ out, int total) {
    int i = blockIdx.x * blockDim.x + threadIdx.x;
    if (i >= total) return;
    out[i] = pool[i] / fmaxf(gcnt[i / 32], 1.f);
}

// ---------------------------------------------------------------------------
extern "C" void kernel_launch(void* const* d_in, const int* in_sizes, int n_in,
                              void* d_out, int out_size, void* d_ws, size_t ws_size,
                              hipStream_t stream) {
    const float* x    = (const float*)d_in[0];
    const int*   ei   = (const int*)d_in[1];
    const int*   batch= (const int*)d_in[2];
    const float* W1   = (const float*)d_in[3];
    const float* as1  = (const float*)d_in[4];
    const float* ad1  = (const float*)d_in[5];
    const float* b1   = (const float*)d_in[6];
    const float* W2   = (const float*)d_in[7];
    const float* as2  = (const float*)d_in[8];
    const float* ad2  = (const float*)d_in[9];
    const float* b2   = (const float*)d_in[10];
    const float* W3   = (const float*)d_in[11];
    const float* as3  = (const float*)d_in[12];
    const float* ad3  = (const float*)d_in[13];
    const float* b3   = (const float*)d_in[14];
    float* out = (float*)d_out;

    const int N  = in_sizes[0] / 128;
    const int E  = in_sizes[1] / 2;
    const int ET = E + N;
    const int G  = 64;
    const int NB = (N + 511) / 512;        // coarse buckets (512 nodes each)

    char* p = (char*)d_ws;
    auto alloc = [&](size_t bytes) {
        char* r = p;
        p += (bytes + 255) & ~(size_t)255;
        return r;
    };
    int*     rp     = (int*)alloc((size_t)(N + 1) * 4);
    int*     bcur   = (int*)alloc(1024);
    int*     cs     = (int*)alloc((size_t)ET * 4);
    ushortT* hA     = (ushortT*)alloc((size_t)N * 64 * 2);  // h1 / h3 (bf16)
    ushortT* hB     = (ushortT*)alloc((size_t)N * 64 * 2);  // h2 (bf16)
    float*   xA     = (float*)alloc((size_t)N * 64 * 4);    // act1 / final act3
    float*   xB     = (float*)alloc((size_t)N * 64 * 4);    // act2
    float*   hs     = (float*)alloc((size_t)N * 4);
    float*   hd     = (float*)alloc((size_t)N * 4);
    float*   pool   = (float*)alloc((size_t)G * 32 * 4);    // 8192 B
    float*   gcnt   = (float*)alloc((size_t)G * 4);         // contiguous after pool
    // ebuf (fixed-cap bucket regions, NB*CAP*4 ~ 12.85MB) aliases xA:
    // local_fill4 (last reader) completes before aggregate-1 writes xA.
    int*     ebuf   = (int*)xA;

    // ---- CSR by destination (shared across all 3 layers) ----
    hipMemsetAsync(bcur, 0, 1024, stream);
    int bb = (ET + 256 * BIN_K - 1) / (256 * BIN_K);
    bin_edges<<<bb, 256, 0, stream>>>(ei, bcur, ebuf, E, ET);
    local_fill4<<<NB, 256, 0, stream>>>(ebuf, bcur, rp, cs, N, NB);

    int gb   = (N + 63) / 64;
    int ab64 = (N + 7) / 8;        // 4 waves/block x 2 nodes/wave
    int ab32 = (N + 15) / 16;      // 4 waves/block x 4 nodes/wave

    // ---- layer 1: 128 -> 64 ----
    gemm_attn<128, 64, 64><<<gb, 256, 0, stream>>>(x, W1, as1, ad1, hA, hs, hd, N);
    aggregate_nf<64, 2><<<ab64, 256, 0, stream>>>(hA, hs, hd, rp, cs, b1, xA, N);
    // ---- layer 2: 64 -> 64 ----
    gemm_attn<64, 64, 64><<<gb, 256, 0, stream>>>(xA, W2, as2, ad2, hB, hs, hd, N);
    aggregate_nf<64, 2><<<ab64, 256, 0, stream>>>(hB, hs, hd, rp, cs, b2, xB, N);
    // ---- layer 3: 64 -> 32 ----
    gemm_attn<64, 32, 64><<<gb, 128, 0, stream>>>(xB, W3, as3, ad3, hA, hs, hd, N);
    aggregate_nf<32, 4><<<ab32, 256, 0, stream>>>(hA, hs, hd, rp, cs, b3, xA, N);

    // ---- global mean pool (pool+gcnt zeroed in ONE memset: contiguous) ----
    hipMemsetAsync(pool, 0, (size_t)G * 32 * 4 + 256, stream);
    pool_kernel<<<(N + 63) / 64, 256, 0, stream>>>(xA, batch, pool, gcnt, N);
    finalize<<<(G * 32 + 255) / 256, 256, 0, stream>>>(pool, gcnt, out, G * 32);
}

// Round 19
// 246.031 us; speedup vs baseline: 1.2847x; 1.2847x over previous
//
#include <hip/hip_runtime.h>
#include <cstdint>
#include <cstddef>

#define NEG_SLOPE 0.2f

typedef unsigned short ushortT;
typedef unsigned int uintT;

// round-to-nearest-even f32 -> bf16 bits (finite values)
__device__ __forceinline__ ushortT f2bf(float f) {
    uintT u = __float_as_uint(f);
    uintT r = (u + 0x7fffu + ((u >> 16) & 1u)) >> 16;
    return (ushortT)r;
}

// ---------------------------------------------------------------------------
// CSR build (2 kernels + 1KB memset): fixed-capacity per-bucket regions.
// bucket = 512 consecutive dst nodes; packed entry = (local_dst<<17)|src
// ---------------------------------------------------------------------------
#define CAP_LOG 14
#define CAP (1 << CAP_LOG)
#define FILL_CAP 12288

#define BIN_K 16   // edges per thread; chunk = 256*16 = 4096
__global__ __launch_bounds__(256) void bin_edges(
    const int* __restrict__ ei, int* __restrict__ bcur,
    int* __restrict__ ebuf, int E, int total) {
    __shared__ int lhist[256];
    __shared__ int lbase[256];
    int tid = threadIdx.x;
    lhist[tid] = 0;
    __syncthreads();
    int base_e = blockIdx.x * (256 * BIN_K);
    int pk[BIN_K], bk[BIN_K];
#pragma unroll
    for (int k = 0; k < BIN_K; ++k) {
        int e = base_e + tid + k * 256;
        bool v = e < total;
        int ee = v ? e : 0;
        int s, d;
        if (ee < E) { s = ei[ee]; d = ei[E + ee]; }
        else        { s = d = ee - E; }
        pk[k] = ((d & 511) << 17) | s;
        bk[k] = v ? (d >> 9) : -1;
        if (v) atomicAdd(&lhist[bk[k]], 1);
    }
    __syncthreads();
    int h = lhist[tid];
    lbase[tid] = (h > 0) ? atomicAdd(&bcur[tid], h) : 0;
    __syncthreads();
    lhist[tid] = 0;
    __syncthreads();
#pragma unroll
    for (int k = 0; k < BIN_K; ++k) {
        if (bk[k] >= 0) {
            int r = atomicAdd(&lhist[bk[k]], 1);
            ebuf[((size_t)bk[k] << CAP_LOG) + lbase[bk[k]] + r] = pk[k];
        }
    }
}

__global__ __launch_bounds__(256) void local_fill4(
    const int* __restrict__ ebuf, const int* __restrict__ bcur,
    int* __restrict__ rp, int* __restrict__ cs, int n, int nb) {
    __shared__ int ebloc[FILL_CAP];
    __shared__ int lhist[512];
    __shared__ int lscan[256];
    __shared__ int lcur[512];
    int b = blockIdx.x;
    int tid = threadIdx.x;
    int node0 = b * 512;
    int nodes = min(512, n - node0);

    int c = (tid < nb) ? bcur[tid] : 0;
    lscan[tid] = c;
    __syncthreads();
    for (int off = 1; off < 256; off <<= 1) {
        int x = (tid >= off) ? lscan[tid - off] : 0;
        __syncthreads();
        lscan[tid] += x;
        __syncthreads();
    }
    int gbase = (b > 0) ? lscan[b - 1] : 0;
    int cnt   = lscan[b] - gbase;
    int total = lscan[nb - 1];
    __syncthreads();

    const int* src_e = ebuf + ((size_t)b << CAP_LOG);
    lhist[tid] = 0; lhist[tid + 256] = 0;
    for (int j = tid; j < cnt && j < FILL_CAP; j += 256)
        ebloc[j] = src_e[j];
    __syncthreads();

    for (int j = tid; j < cnt; j += 256) {
        int v = (j < FILL_CAP) ? ebloc[j] : src_e[j];
        atomicAdd(&lhist[v >> 17], 1);
    }
    __syncthreads();

    int a0 = lhist[2 * tid], a1 = lhist[2 * tid + 1];
    int psum = a0 + a1;
    lscan[tid] = psum;
    __syncthreads();
    for (int off = 1; off < 256; off <<= 1) {
        int x = (tid >= off) ? lscan[tid - off] : 0;
        __syncthreads();
        lscan[tid] += x;
        __syncthreads();
    }
    int e0 = gbase + (lscan[tid] - psum);
    int e1 = e0 + a0;
    if (2 * tid < nodes)     rp[node0 + 2 * tid]     = e0;
    if (2 * tid + 1 < nodes) rp[node0 + 2 * tid + 1] = e1;
    lcur[2 * tid] = e0;
    lcur[2 * tid + 1] = e1;
    if (b == 0 && tid == 0) rp[n] = total;
    __syncthreads();

    for (int j = tid; j < cnt; j += 256) {
        int v = (j < FILL_CAP) ? ebloc[j] : src_e[j];
        int pos = atomicAdd(&lcur[v >> 17], 1);
        cs[pos] = v & 0x1FFFF;
    }
}

// ---------------------------------------------------------------------------
// Fused projection + attention dots:  h(bf16) = x @ W ; hs/hd from f32 acc.
// R14 form (best measured): simple unroll-2 k-loop, 36 VGPR — the compiler's
// own schedule beats all four manual pipelining attempts (R15-R18).
// ---------------------------------------------------------------------------
template <int INF, int OUTF>
__global__ void gemm_attn(const float* __restrict__ x, const float* __restrict__ W,
                          const float* __restrict__ a_s, const float* __restrict__ a_d,
                          ushortT* __restrict__ h, float* __restrict__ hs,
                          float* __restrict__ hd, int n) {
    constexpr int FC  = OUTF / 4;
    constexpr int NPB = 64;
    constexpr int NT  = FC * (NPB / 4);
    __shared__ float Wl[INF * OUTF];
    int tid = threadIdx.x;
    for (int i = tid; i < INF * OUTF; i += NT) Wl[i] = W[i];
    __syncthreads();

    int fc = tid % FC;
    int nc = tid / FC;
    int n0 = blockIdx.x * NPB + nc * 4;
    int ni[4];
#pragma unroll
    for (int i = 0; i < 4; ++i) { int v = n0 + i; ni[i] = (v < n) ? v : (n - 1); }

    float acc[4][4] = {};
#pragma unroll 2
    for (int k = 0; k < INF; k += 4) {
        float4 xv[4];
#pragma unroll
        for (int i = 0; i < 4; ++i)
            xv[i] = *reinterpret_cast<const float4*>(&x[(size_t)ni[i] * INF + k]);
#pragma unroll
        for (int j = 0; j < 4; ++j) {
            float4 wv = *reinterpret_cast<const float4*>(&Wl[(k + j) * OUTF + fc * 4]);
#pragma unroll
            for (int i = 0; i < 4; ++i) {
                float xs = (&xv[i].x)[j];
                acc[i][0] = fmaf(xs, wv.x, acc[i][0]);
                acc[i][1] = fmaf(xs, wv.y, acc[i][1]);
                acc[i][2] = fmaf(xs, wv.z, acc[i][2]);
                acc[i][3] = fmaf(xs, wv.w, acc[i][3]);
            }
        }
    }

    float asv[4], adv[4];
#pragma unroll
    for (int j = 0; j < 4; ++j) { asv[j] = a_s[fc * 4 + j]; adv[j] = a_d[fc * 4 + j]; }

#pragma unroll
    for (int i = 0; i < 4; ++i) {
        float ps = acc[i][0] * asv[0] + acc[i][1] * asv[1] +
                   acc[i][2] * asv[2] + acc[i][3] * asv[3];
        float pd = acc[i][0] * adv[0] + acc[i][1] * adv[1] +
                   acc[i][2] * adv[2] + acc[i][3] * adv[3];
#pragma unroll
        for (int off = FC >> 1; off; off >>= 1) {
            ps += __shfl_xor(ps, off, FC);
            pd += __shfl_xor(pd, off, FC);
        }
        int node = n0 + i;
        if (node < n) {
            ushort4 hv;
            hv.x = f2bf(acc[i][0]); hv.y = f2bf(acc[i][1]);
            hv.z = f2bf(acc[i][2]); hv.w = f2bf(acc[i][3]);
            *reinterpret_cast<ushort4*>(&h[(size_t)node * OUTF + fc * 4]) = hv;
            if (fc == 0) { hs[node] = ps; hd[node] = pd; }
        }
    }
}

// ---------------------------------------------------------------------------
// Multi-node-per-wave softmax aggregation over bf16 h rows, no online max
// (logits provably bounded |l|<~3). NPN node groups of LPN=64/NPN lanes;
// eL = F/8 lanes per edge (uint4 = 8 bf16 each); EPS = LPN/eL edges/step.
// ---------------------------------------------------------------------------
template <int F, int NPN>
__global__ __launch_bounds__(256) void aggregate_nf(
    const ushortT* __restrict__ hb, const float* __restrict__ hs,
    const float* __restrict__ hd, const int* __restrict__ rp,
    const int* __restrict__ cs, const float* __restrict__ b,
    float* __restrict__ out, int n) {
    constexpr int LPN = 64 / NPN;          // lanes per node group
    constexpr int eL  = F / 8;             // lanes per edge
    constexpr int EPS = LPN / eL;          // edges per step
    int wid  = (blockIdx.x * blockDim.x + threadIdx.x) >> 6;
    int lane = threadIdx.x & 63;
    int fl   = lane % LPN;
    int node = wid * NPN + lane / LPN;
    if (node >= n) return;
    int beg = rp[node], end = rp[node + 1];
    float hdn = hd[node];

    int grp = fl / eL;                     // 0..EPS-1: edge slot within step
    int sub = fl % eL;                     // feature-8-block index
    float4 bbA = *reinterpret_cast<const float4*>(&b[sub * 8]);
    float4 bbB = *reinterpret_cast<const float4*>(&b[sub * 8 + 4]);

    float sl = 0.f;                        // lane-local weight sum
    float acc[8] = {};

    for (int base = beg; base < end; base += LPN) {
        int e = base + fl;
        bool v = e < end;
        int src = cs[v ? e : beg];         // clamped: always a valid row

        float l = hs[src] + hdn;
        l = (l > 0.f) ? l : NEG_SLOPE * l;
        float w = v ? __expf(l) : 0.f;     // bounded: |l| < ~3
        sl += w;

        int cc = min(LPN, end - base);
        for (int t = 0; t * EPS < cc; t += 2) {
            uint4 hv[2];
            float wv[2];
#pragma unroll
            for (int u = 0; u < 2; ++u) {
                int jj = (t + u) * EPS + grp;       // < LPN by construction
                int   se = __shfl(src, jj, LPN);
                wv[u]    = __shfl(w,   jj, LPN);
                hv[u] = *reinterpret_cast<const uint4*>(&hb[(size_t)se * F + sub * 8]);
            }
#pragma unroll
            for (int u = 0; u < 2; ++u) {
                uintT q[4] = {hv[u].x, hv[u].y, hv[u].z, hv[u].w};
#pragma unroll
                for (int i = 0; i < 4; ++i) {
                    float lo = __uint_as_float(q[i] << 16);
                    float hi = __uint_as_float(q[i] & 0xffff0000u);
                    acc[2 * i]     = fmaf(wv[u], lo, acc[2 * i]);
                    acc[2 * i + 1] = fmaf(wv[u], hi, acc[2 * i + 1]);
                }
            }
        }
    }

#pragma unroll
    for (int off = LPN >> 1; off; off >>= 1)
        sl += __shfl_xor(sl, off, LPN);

#pragma unroll
    for (int off = eL; off < LPN; off <<= 1) {
#pragma unroll
        for (int i = 0; i < 8; ++i)
            acc[i] += __shfl_xor(acc[i], off, LPN);
    }

    float inv = 1.f / (sl + 1e-16f);
    if (grp == 0) {
        float4 rA, rB;
        rA.x = fmaxf(fmaf(acc[0], inv, bbA.x), 0.f);
        rA.y = fmaxf(fmaf(acc[1], inv, bbA.y), 0.f);
        rA.z = fmaxf(fmaf(acc[2], inv, bbA.z), 0.f);
        rA.w = fmaxf(fmaf(acc[3], inv, bbA.w), 0.f);
        rB.x = fmaxf(fmaf(acc[4], inv, bbB.x), 0.f);
        rB.y = fmaxf(fmaf(acc[5], inv, bbB.y), 0.f);
        rB.z = fmaxf(fmaf(acc[6], inv, bbB.z), 0.f);
        rB.w = fmaxf(fmaf(acc[7], inv, bbB.w), 0.f);
        *reinterpret_cast<float4*>(&out[(size_t)node * F + sub * 8])     = rA;
        *reinterpret_cast<float4*>(&out[(size_t)node * F + sub * 8 + 4]) = rB;
    }
}

// ---------------------------------------------------------------------------
// Global mean pool (batch is sorted): LDS pre-reduction then global atomics
// ---------------------------------------------------------------------------
__global__ void pool_kernel(const float* __restrict__ x, const int* __restrict__ batch,
                            float* __restrict__ pool, float* __restrict__ gcnt, int n) {
    __shared__ float lp[64 * 32];
    __shared__ float lc[64];
    int tid = threadIdx.x;
    for (int i = tid; i < 64 * 32; i += 256) lp[i] = 0.f;
    if (tid < 64) lc[tid] = 0.f;
    __syncthreads();
    int f = tid % 32, r = tid / 32;
    int base = blockIdx.x * 64;
    for (int i = r; i < 64; i += 8) {
        int node = base + i;
        if (node < n) {
            int g = batch[node];
            atomicAdd(&lp[g * 32 + f], x[(size_t)node * 32 + f]);
            if (f == 0) atomicAdd(&lc[g], 1.f);
        }
    }
    __syncthreads();
    for (int i = tid; i < 64 * 32; i += 256)
        if (lp[i] != 0.f) atomicAdd(&pool[i], lp[i]);
    if (tid < 64 && lc[tid] != 0.f) atomicAdd(&gcnt[tid], lc[tid]);
}

__global__ void finalize(const float* __restrict__ pool, const float* __restrict__ gcnt,
                         float* __restrict__ out, int total) {
    int i = blockIdx.x * blockDim.x + threadIdx.x;
    if (i >= total) return;
    out[i] = pool[i] / fmaxf(gcnt[i / 32], 1.f);
}

// ---------------------------------------------------------------------------
extern "C" void kernel_launch(void* const* d_in, const int* in_sizes, int n_in,
                              void* d_out, int out_size, void* d_ws, size_t ws_size,
                              hipStream_t stream) {
    const float* x    = (const float*)d_in[0];
    const int*   ei   = (const int*)d_in[1];
    const int*   batch= (const int*)d_in[2];
    const float* W1   = (const float*)d_in[3];
    const float* as1  = (const float*)d_in[4];
    const float* ad1  = (const float*)d_in[5];
    const float* b1   = (const float*)d_in[6];
    const float* W2   = (const float*)d_in[7];
    const float* as2  = (const float*)d_in[8];
    const float* ad2  = (const float*)d_in[9];
    const float* b2   = (const float*)d_in[10];
    const float* W3   = (const float*)d_in[11];
    const float* as3  = (const float*)d_in[12];
    const float* ad3  = (const float*)d_in[13];
    const float* b3   = (const float*)d_in[14];
    float* out = (float*)d_out;

    const int N  = in_sizes[0] / 128;
    const int E  = in_sizes[1] / 2;
    const int ET = E + N;
    const int G  = 64;
    const int NB = (N + 511) / 512;        // coarse buckets (512 nodes each)

    char* p = (char*)d_ws;
    auto alloc = [&](size_t bytes) {
        char* r = p;
        p += (bytes + 255) & ~(size_t)255;
        return r;
    };
    int*     rp     = (int*)alloc((size_t)(N + 1) * 4);
    int*     bcur   = (int*)alloc(1024);
    int*     cs     = (int*)alloc((size_t)ET * 4);
    ushortT* hA     = (ushortT*)alloc((size_t)N * 64 * 2);  // h1 / h3 (bf16)
    ushortT* hB     = (ushortT*)alloc((size_t)N * 64 * 2);  // h2 (bf16)
    float*   xA     = (float*)alloc((size_t)N * 64 * 4);    // act1 / final act3
    float*   xB     = (float*)alloc((size_t)N * 64 * 4);    // act2
    float*   hs     = (float*)alloc((size_t)N * 4);
    float*   hd     = (float*)alloc((size_t)N * 4);
    float*   pool   = (float*)alloc((size_t)G * 32 * 4);    // 8192 B
    float*   gcnt   = (float*)alloc((size_t)G * 4);         // contiguous after pool
    // ebuf (fixed-cap bucket regions, NB*CAP*4 ~ 12.85MB) aliases xA:
    // local_fill4 (last reader) completes before aggregate-1 writes xA.
    int*     ebuf   = (int*)xA;

    // ---- CSR by destination (shared across all 3 layers) ----
    hipMemsetAsync(bcur, 0, 1024, stream);
    int bb = (ET + 256 * BIN_K - 1) / (256 * BIN_K);
    bin_edges<<<bb, 256, 0, stream>>>(ei, bcur, ebuf, E, ET);
    local_fill4<<<NB, 256, 0, stream>>>(ebuf, bcur, rp, cs, N, NB);

    int gb   = (N + 63) / 64;
    int ab64 = (N + 7) / 8;        // 4 waves/block x 2 nodes/wave
    int ab32 = (N + 15) / 16;      // 4 waves/block x 4 nodes/wave

    // ---- layer 1: 128 -> 64 ----
    gemm_attn<128, 64><<<gb, 256, 0, stream>>>(x, W1, as1, ad1, hA, hs, hd, N);
    aggregate_nf<64, 2><<<ab64, 256, 0, stream>>>(hA, hs, hd, rp, cs, b1, xA, N);
    // ---- layer 2: 64 -> 64 ----
    gemm_attn<64, 64><<<gb, 256, 0, stream>>>(xA, W2, as2, ad2, hB, hs, hd, N);
    aggregate_nf<64, 2><<<ab64, 256, 0, stream>>>(hB, hs, hd, rp, cs, b2, xB, N);
    // ---- layer 3: 64 -> 32 ----
    gemm_attn<64, 32><<<gb, 128, 0, stream>>>(xB, W3, as3, ad3, hA, hs, hd, N);
    aggregate_nf<32, 4><<<ab32, 256, 0, stream>>>(hA, hs, hd, rp, cs, b3, xA, N);

    // ---- global mean pool (pool+gcnt zeroed in ONE memset: contiguous) ----
    hipMemsetAsync(pool, 0, (size_t)G * 32 * 4 + 256, stream);
    pool_kernel<<<(N + 63) / 64, 256, 0, stream>>>(xA, batch, pool, gcnt, N);
    finalize<<<(G * 32 + 255) / 256, 256, 0, stream>>>(pool, gcnt, out, G * 32);
}